// Round 16
// baseline (726.007 us; speedup 1.0000x reference)
//
#include <hip/hip_runtime.h>
#include <hip/hip_cooperative_groups.h>

namespace cg = cooperative_groups;

// ---------------------------------------------------------------------------
// ReactionGCN: 3-layer GCN (GCNConv + BN + ReLU) -> global_mean_pool -> MLP
// bf16 activations end-to-end (fp32 accumulation):
//   - graph build = ONE cooperative kernel (zero+goff / bucket-count / scan /
//     partition / CSR place, grid.sync between phases)
//   - GEMM = MFMA 16x16x32 bf16, A direct from global; BN affine computed
//     in-kernel from 64-replica stats and folded into the LDS B-tile
//   - aggregation: one wave per node, 16 gathers in flight (bit-stable floor)
//   - BN stats: separate kernel writing replica (blockIdx&63)
//   - pool+MLP fused, final affine from replicas inline
// ---------------------------------------------------------------------------

typedef __attribute__((ext_vector_type(8))) short short8;
typedef __attribute__((ext_vector_type(4))) float f32x4;

__device__ inline unsigned f32_to_bf16_rne(float f) {
  unsigned u = __float_as_uint(f);
  unsigned r = 0x7fffu + ((u >> 16) & 1u);
  return (u + r) >> 16;
}
__device__ inline unsigned pack2_bf16(float lo, float hi) {
  return f32_to_bf16_rne(lo) | (f32_to_bf16_rne(hi) << 16);
}
__device__ inline float bf16_lo(unsigned u) { return __uint_as_float(u << 16); }
__device__ inline float bf16_hi(unsigned u) { return __uint_as_float(u & 0xffff0000u); }

#define PCH 4096
#define NBUK_MAX 1024
#define NREP 64          // stats replicas per layer
#define REPSZ 256        // floats per replica: [0:128]=ssum, [128:256]=ssq
#define LAYER_STATS (NREP * REPSZ)
#define CSR_GRID 512     // 2 blocks/CU guaranteed at 44KB LDS

// -------------------- cooperative graph-structure build ---------------------
// phase0: zero bcnt+stats, goff binsearch | phase1: bucket histogram |
// phase2: bucket scan (block 0) | phase3: partition | phase4: CSR place+dis
__global__ __launch_bounds__(256) void k_graph(const int* __restrict__ src,
                                               const int* __restrict__ dst,
                                               const int* __restrict__ batch,
                                               int* __restrict__ bcnt,
                                               int* __restrict__ bof,
                                               int* __restrict__ bcur,
                                               unsigned* __restrict__ ebuf,
                                               int* __restrict__ eoff,
                                               float* __restrict__ dis,
                                               int* __restrict__ csr_src,
                                               float* __restrict__ stats,
                                               int* __restrict__ goff,
                                               int N, int E, int G, int nbuk, int nstats) {
  cg::grid_group grid = cg::this_grid();
  __shared__ int hist[NBUK_MAX];
  __shared__ int lofs[NBUK_MAX];
  __shared__ int gbase[NBUK_MAX];
  __shared__ uint2 stage[PCH];
  int t = threadIdx.x;
  int nb = gridDim.x;
  int gtid = blockIdx.x * 256 + t;
  int gstride = nb * 256;

  // ---- phase 0: zero bcnt + stats, compute goff ----
  for (int i = gtid; i < nstats; i += gstride) stats[i] = 0.f;
  for (int i = gtid; i < nbuk; i += gstride) bcnt[i] = 0;
  for (int i = gtid; i <= G; i += gstride) {
    int lo = 0, hi = N;
    while (lo < hi) { int m = (lo + hi) >> 1; if (batch[m] < i) lo = m + 1; else hi = m; }
    goff[i] = lo;
  }
  __threadfence();
  grid.sync();

  // ---- phase 1: bucket counts via LDS histogram ----
  for (int i = t; i < nbuk; i += 256) hist[i] = 0;
  __syncthreads();
  for (int e = gtid; e < E; e += gstride)
    atomicAdd(&hist[((unsigned)dst[e]) >> 7], 1);
  __syncthreads();
  for (int i = t; i < nbuk; i += 256) {
    int h = hist[i];
    if (h) atomicAdd(&bcnt[i], h);
  }
  __threadfence();
  grid.sync();

  // ---- phase 2: exclusive scan bcnt -> bof, bcur (block 0 only) ----
  if (blockIdx.x == 0) {
    int base = t * 4;
    int v[4]; int s = 0;
#pragma unroll
    for (int k = 0; k < 4; ++k) { v[k] = (base + k < nbuk) ? bcnt[base + k] : 0; s += v[k]; }
    int lane = t & 63, wv = t >> 6;
    int x = s;
#pragma unroll
    for (int d = 1; d < 64; d <<= 1) { int y = __shfl_up(x, d); if (lane >= d) x += y; }
    __shared__ int wsum[4];
    if (lane == 63) wsum[wv] = x;
    __syncthreads();
    int woff = 0;
    for (int w = 0; w < wv; ++w) woff += wsum[w];
    int run = woff + x - s;
#pragma unroll
    for (int k = 0; k < 4; ++k) {
      if (base + k < nbuk) { bof[base + k] = run; bcur[base + k] = run; }
      run += v[k];
    }
    if (t == 0) bof[nbuk] = E;
  }
  __threadfence();
  grid.sync();

  // ---- phase 3: partition edges into bucket regions ----
  // record = (src<<7) | (dst&127); bucket = dst>>7.
  int nch = (E + PCH - 1) / PCH;
  for (int ch = blockIdx.x; ch < nch; ch += nb) {
    int e0 = ch * PCH;
    int cnt = E - e0; if (cnt > PCH) cnt = PCH;
    for (int i = t; i < nbuk; i += 256) hist[i] = 0;
    __syncthreads();
    uint2 ev[PCH / 256];
#pragma unroll
    for (int k = 0; k < PCH / 256; ++k) {
      int i = t + k * 256;
      uint2 r = make_uint2(0u, 0u);
      if (i < cnt) {
        r = make_uint2((unsigned)src[e0 + i], (unsigned)dst[e0 + i]);
        atomicAdd(&hist[r.y >> 7], 1);
      }
      ev[k] = r;
    }
    __syncthreads();
    if (t < 64) {
      int run = 0;
      for (int c0 = 0; c0 < nbuk; c0 += 64) {
        int idx = c0 + t;
        int v = (idx < nbuk) ? hist[idx] : 0;
        int x = v;
#pragma unroll
        for (int dlt = 1; dlt < 64; dlt <<= 1) { int y = __shfl_up(x, dlt); if (t >= dlt) x += y; }
        if (idx < nbuk) lofs[idx] = run + x - v;
        run += __shfl(x, 63);
      }
    }
    __syncthreads();
    for (int i = t; i < nbuk; i += 256) {
      int h = hist[i];
      if (h > 0) gbase[i] = atomicAdd(&bcur[i], h);
      hist[i] = 0;
    }
    __syncthreads();
#pragma unroll
    for (int k = 0; k < PCH / 256; ++k) {
      int i = t + k * 256;
      if (i < cnt) {
        uint2 r = ev[k];
        int bk = (int)(r.y >> 7);
        unsigned packed = (r.x << 7) | (r.y & 127u);
        int rank = atomicAdd(&hist[bk], 1);
        stage[lofs[bk] + rank] = make_uint2(packed, (unsigned)bk);
      }
    }
    __syncthreads();
    for (int j = t; j < cnt; j += 256) {
      uint2 s = stage[j];
      int bk = (int)s.y;
      ebuf[(size_t)gbase[bk] + (j - lofs[bk])] = s.x;
    }
    __syncthreads();
  }
  __threadfence();
  grid.sync();

  // ---- phase 4: per-bucket deg/eoff/dis + CSR place (reuse hist/lofs) ----
  for (int b = blockIdx.x; b < nbuk; b += nb) {
    int n0 = b * 128;
    int nn = N - n0; if (nn > 128) nn = 128;
    int e0 = bof[b], e1 = bof[b + 1];
    if (t < 128) hist[t] = 0;    // lcnt
    __syncthreads();
    for (int j = e0 + t; j < e1; j += 256) atomicAdd(&hist[ebuf[j] & 127u], 1);
    __syncthreads();
    if (t < 64) {
      int run = 0;
      for (int c0 = 0; c0 < 128; c0 += 64) {
        int v = hist[c0 + t];
        int x = v;
#pragma unroll
        for (int d = 1; d < 64; d <<= 1) { int y = __shfl_up(x, d); if (t >= d) x += y; }
        lofs[c0 + t] = run + x - v;   // loff
        run += __shfl(x, 63);
      }
    }
    __syncthreads();
    if (t < nn) {
      eoff[n0 + t] = e0 + lofs[t];
      dis[n0 + t] = 1.0f / sqrtf((float)hist[t] + 1.0f);
    }
    if (b == nbuk - 1 && t == nn) eoff[n0 + nn] = E;
    __syncthreads();
    if (t < 128) hist[t] = 0;    // reuse as cursor
    __syncthreads();
    for (int j = e0 + t; j < e1; j += 256) {
      unsigned r = ebuf[j];
      int loc = (int)(r & 127u);
      int rank = atomicAdd(&hist[loc], 1);
      csr_src[e0 + lofs[loc] + rank] = (int)(r >> 7);
    }
    __syncthreads();
  }
}

// -------------------- MFMA GEMM with in-kernel BN fold ----------------------
// outb = bf16(dis[r] * (X @ (a.*W) + sum_k c[k]W[k,:]))
template <bool AFP32, bool IDENT>
__global__ __launch_bounds__(512) void k_gemm_mfma(const void* __restrict__ Xv,
                                                   const float* __restrict__ Wn,
                                                   const float* __restrict__ gamma,
                                                   const float* __restrict__ beta,
                                                   const float* __restrict__ statsL,
                                                   const float* __restrict__ dis,
                                                   unsigned* __restrict__ outb,
                                                   int nrows, float invn) {
  __shared__ uint4 Bsm[2048];          // 32KB folded W, fragment-packed
  __shared__ float as_[128], cs_[128], b2[128];
  int t = threadIdx.x;
  if (t < 128) {
    float a, c;
    if (IDENT) { a = 1.f; c = 0.f; }
    else {
      float s = 0.f, q = 0.f;
#pragma unroll 8
      for (int r = 0; r < NREP; ++r) {
        s += statsL[r * REPSZ + t];
        q += statsL[r * REPSZ + 128 + t];
      }
      float mu  = s * invn;
      float var = q * invn - mu * mu;
      a = gamma[t] / sqrtf(var + 1e-5f);
      c = beta[t] - mu * a;
    }
    as_[t] = a; cs_[t] = c; b2[t] = 0.f;
  }
  __syncthreads();
#pragma unroll
  for (int it = 0; it < 4; ++it) {
    int item = it * 512 + t;
    int lane = item & 63, bk = (item >> 6) & 7, kstep = item >> 9;
    int col = bk * 16 + (lane & 15);
    int kb = kstep * 32 + ((lane >> 4) << 2);
    unsigned o[4];
    float bp = 0.f;
#pragma unroll
    for (int hh = 0; hh < 2; ++hh)
#pragma unroll
      for (int pp = 0; pp < 2; ++pp) {
        int k0 = kb + hh * 16 + pp * 2;
        float wA = Wn[(size_t)k0 * 128 + col];
        float wB = Wn[(size_t)(k0 + 1) * 128 + col];
        o[hh * 2 + pp] = pack2_bf16(as_[k0] * wA, as_[k0 + 1] * wB);
        bp = fmaf(cs_[k0], wA, fmaf(cs_[k0 + 1], wB, bp));
      }
    Bsm[item] = make_uint4(o[0], o[1], o[2], o[3]);
    atomicAdd(&b2[col], bp);
  }
  __syncthreads();

  int w = t >> 6, l = t & 63;
  int row0 = blockIdx.x * 128 + w * 16;
  int arow = row0 + (l & 15);
  int kgrp = l >> 4;
  bool aval = arow < nrows;
  f32x4 acc[8];
#pragma unroll
  for (int i = 0; i < 8; ++i) acc[i] = (f32x4){0.f, 0.f, 0.f, 0.f};
#pragma unroll
  for (int kk = 0; kk < 4; ++kk) {
    union { uint4 u; short8 s; } af;
    if (AFP32) {
      const float4* X = (const float4*)Xv;
      float4 v0 = make_float4(0.f, 0.f, 0.f, 0.f), v1 = v0;
      if (aval) {
        size_t bi = (size_t)arow * 32 + kk * 8 + kgrp;
        v0 = X[bi];
        v1 = X[bi + 4];
      }
      af.u = make_uint4(pack2_bf16(v0.x, v0.y), pack2_bf16(v0.z, v0.w),
                        pack2_bf16(v1.x, v1.y), pack2_bf16(v1.z, v1.w));
    } else {
      const uint2* X = (const uint2*)Xv;
      uint2 lo = make_uint2(0, 0), hi = lo;
      if (aval) {
        size_t bi = (size_t)arow * 32 + kk * 8 + kgrp;
        lo = X[bi];
        hi = X[bi + 4];
      }
      af.u = make_uint4(lo.x, lo.y, hi.x, hi.y);
    }
#pragma unroll
    for (int ct = 0; ct < 8; ++ct) {
      union { uint4 u; short8 s; } bf;
      bf.u = Bsm[(kk * 8 + ct) * 64 + l];
      acc[ct] = __builtin_amdgcn_mfma_f32_16x16x32_bf16(af.s, bf.s, acc[ct], 0, 0, 0);
    }
  }
  int dcol = l & 15;
#pragma unroll
  for (int r = 0; r < 4; ++r) {
    int grow = row0 + kgrp * 4 + r;
    if (grow < nrows) {
      float dr = dis[grow];
#pragma unroll
      for (int ct = 0; ct < 8; ++ct) {
        int col = ct * 16 + dcol;
        float v = (acc[ct][r] + b2[col]) * dr;
        ((unsigned short*)outb)[(size_t)grow * 128 + col] = (unsigned short)f32_to_bf16_rne(v);
      }
    }
  }
}

// -------------------- aggregation (one wave per node, 16 gathers in flight) -
__global__ __launch_bounds__(256) void k_aggregate(const unsigned* __restrict__ hWb,
                                                   const int* __restrict__ eoff,
                                                   const int* __restrict__ csr_src,
                                                   const float* __restrict__ dis,
                                                   const float* __restrict__ bias,
                                                   unsigned* __restrict__ h2b, int N) {
  int node = __builtin_amdgcn_readfirstlane((int)((blockIdx.x * 256 + threadIdx.x) >> 6));
  int lane = threadIdx.x & 63;
  if (node >= N) return;
  unsigned su = hWb[(size_t)node * 64 + lane];
  float a0 = bf16_lo(su), a1 = bf16_hi(su);
  int p  = eoff[node];
  int e1 = eoff[node + 1];
  int rem = e1 - p;
  while (rem >= 16) {
    int sx[16];
#pragma unroll
    for (int k = 0; k < 16; ++k) sx[k] = csr_src[p + k];
    p += 16; rem -= 16;
    unsigned ux[16];
#pragma unroll
    for (int k = 0; k < 16; ++k) ux[k] = hWb[(size_t)sx[k] * 64 + lane];
#pragma unroll
    for (int k = 0; k < 16; ++k) { a0 += bf16_lo(ux[k]); a1 += bf16_hi(ux[k]); }
  }
  while (rem >= 4) {
    int s0 = csr_src[p], s1 = csr_src[p + 1], s2 = csr_src[p + 2], s3 = csr_src[p + 3];
    p += 4; rem -= 4;
    unsigned u0 = hWb[(size_t)s0 * 64 + lane], u1 = hWb[(size_t)s1 * 64 + lane];
    unsigned u2 = hWb[(size_t)s2 * 64 + lane], u3 = hWb[(size_t)s3 * 64 + lane];
    a0 += bf16_lo(u0); a1 += bf16_hi(u0);
    a0 += bf16_lo(u1); a1 += bf16_hi(u1);
    a0 += bf16_lo(u2); a1 += bf16_hi(u2);
    a0 += bf16_lo(u3); a1 += bf16_hi(u3);
  }
  while (rem) {
    unsigned u0 = hWb[(size_t)csr_src[p] * 64 + lane];
    ++p; --rem;
    a0 += bf16_lo(u0); a1 += bf16_hi(u0);
  }
  float dd = dis[node];
  float2 bb = ((const float2*)bias)[lane];
  float v0 = fmaf(dd, a0, bb.x);
  float v1 = fmaf(dd, a1, bb.y);
  h2b[(size_t)node * 64 + lane] = pack2_bf16(fmaxf(v0, 0.f), fmaxf(v1, 0.f));
}

// -------------------- BN stats on bf16 h2 -> replica (blockIdx&63) ----------
__global__ __launch_bounds__(256) void k_stats_b(const unsigned* __restrict__ h2b,
                                                 float* __restrict__ statsL, int N) {
  int c = threadIdx.x & 63;
  int q = threadIdx.x >> 6;
  int r0 = blockIdx.x * 256;
  int r1 = r0 + 256; if (r1 > N) r1 = N;
  float s0 = 0.f, q0 = 0.f, s1 = 0.f, q1 = 0.f;
  for (int r = r0 + q; r < r1; r += 4) {
    unsigned u = h2b[(size_t)r * 64 + c];
    float h0 = bf16_lo(u), h1 = bf16_hi(u);
    s0 += h0; q0 = fmaf(h0, h0, q0);
    s1 += h1; q1 = fmaf(h1, h1, q1);
  }
  __shared__ float red[4][256];
  int t = threadIdx.x;
  red[0][t] = s0; red[1][t] = q0; red[2][t] = s1; red[3][t] = q1;
  __syncthreads();
  if (t < 64) {
    float S0 = red[0][t] + red[0][t + 64] + red[0][t + 128] + red[0][t + 192];
    float Q0 = red[1][t] + red[1][t + 64] + red[1][t + 128] + red[1][t + 192];
    float S1 = red[2][t] + red[2][t + 64] + red[2][t + 128] + red[2][t + 192];
    float Q1 = red[3][t] + red[3][t + 64] + red[3][t + 128] + red[3][t + 192];
    float* srep = statsL + (size_t)(blockIdx.x & (NREP - 1)) * REPSZ;
    atomicAdd(&srep[2 * t], S0);        atomicAdd(&srep[2 * t + 1], S1);
    atomicAdd(&srep[128 + 2 * t], Q0);  atomicAdd(&srep[128 + 2 * t + 1], Q1);
  }
}

// -------------------- fused pooling + MLP (replica affine inline) -----------
__global__ __launch_bounds__(256) void k_pool_mlp(const unsigned* __restrict__ h2b,
                                                  const int* __restrict__ goff,
                                                  const float* __restrict__ gamma2,
                                                  const float* __restrict__ beta2,
                                                  const float* __restrict__ statsL,
                                                  const float* __restrict__ hw1,
                                                  const float* __restrict__ hb1,
                                                  const float* __restrict__ hw2,
                                                  const float* __restrict__ hb2,
                                                  float* __restrict__ out, int G, float invn) {
  __shared__ float av_[128], cv_[128];
  __shared__ float pl[4][128];
  int t = threadIdx.x;
  if (t < 128) {
    float s = 0.f, q = 0.f;
#pragma unroll 8
    for (int r = 0; r < NREP; ++r) {
      s += statsL[r * REPSZ + t];
      q += statsL[r * REPSZ + 128 + t];
    }
    float mu  = s * invn;
    float var = q * invn - mu * mu;
    float a = gamma2[t] / sqrtf(var + 1e-5f);
    av_[t] = a;
    cv_[t] = beta2[t] - mu * a;
  }
  __syncthreads();
  int g = __builtin_amdgcn_readfirstlane((int)((blockIdx.x * 256 + t) >> 6));
  int lane = t & 63;
  int w = t >> 6;
  if (g >= G) return;
  int r0 = goff[g], r1 = goff[g + 1];
  float s0 = 0.f, s1 = 0.f;
  int r = r0;
  while (r + 4 <= r1) {
    unsigned u0 = h2b[(size_t)(r + 0) * 64 + lane];
    unsigned u1 = h2b[(size_t)(r + 1) * 64 + lane];
    unsigned u2 = h2b[(size_t)(r + 2) * 64 + lane];
    unsigned u3 = h2b[(size_t)(r + 3) * 64 + lane];
    r += 4;
    s0 += bf16_lo(u0); s1 += bf16_hi(u0);
    s0 += bf16_lo(u1); s1 += bf16_hi(u1);
    s0 += bf16_lo(u2); s1 += bf16_hi(u2);
    s0 += bf16_lo(u3); s1 += bf16_hi(u3);
  }
  while (r < r1) {
    unsigned u = h2b[(size_t)r * 64 + lane];
    ++r;
    s0 += bf16_lo(u); s1 += bf16_hi(u);
  }
  float p0 = 0.f, p1 = 0.f;
  if (r1 > r0) {
    float inv = 1.0f / (float)(r1 - r0);
    float2 av = *(const float2*)&av_[2 * lane];
    float2 cv = *(const float2*)&cv_[2 * lane];
    p0 = fmaf(av.x, s0 * inv, cv.x);
    p1 = fmaf(av.y, s1 * inv, cv.y);
  }
  pl[w][2 * lane]     = p0;
  pl[w][2 * lane + 1] = p1;
  float acc = hb1[lane];
  for (int f = 0; f < 128; ++f) acc = fmaf(pl[w][f], hw1[f * 64 + lane], acc);
  acc = fmaxf(acc, 0.f) * hw2[lane];
  for (int d = 32; d; d >>= 1) acc += __shfl_down(acc, d);
  if (lane == 0) out[g] = acc + hb2[0];
}

// ---------------------------------------------------------------------------
extern "C" void kernel_launch(void* const* d_in, const int* in_sizes, int n_in,
                              void* d_out, int out_size, void* d_ws, size_t ws_size,
                              hipStream_t stream) {
  const float* x     = (const float*)d_in[0];
  const int*   ei    = (const int*)d_in[1];
  const int*   batch = (const int*)d_in[2];
  const float* W     = (const float*)d_in[3];
  const float* b     = (const float*)d_in[4];
  const float* gamma = (const float*)d_in[5];
  const float* beta  = (const float*)d_in[6];
  const float* hw1   = (const float*)d_in[7];
  const float* hb1   = (const float*)d_in[8];
  const float* hw2   = (const float*)d_in[9];
  const float* hb2   = (const float*)d_in[10];
  float* out = (float*)d_out;

  const int F = 128;
  const int N = in_sizes[0] / F;
  const int E = in_sizes[1] / 2;
  const int G = out_size;
  const int nbuk = (N + 127) / 128;
  const int nstats = 3 * LAYER_STATS;   // 49152 floats
  const float invn = 1.0f / (float)N;

  const int* esrc = ei;
  const int* edst = ei + E;

  // ---- workspace carve ----
  char* wp = (char*)d_ws;
  auto alloc = [&](size_t bytes) -> void* {
    void* r = (void*)wp;
    wp += (bytes + 255) & ~(size_t)255;
    return r;
  };
  unsigned* hWb   = (unsigned*)alloc((size_t)N * 64 * 4);
  unsigned* h2b   = (unsigned*)alloc((size_t)N * 64 * 4);
  float* dis      = (float*)alloc((size_t)N * 4);
  int*   eoff     = (int*)alloc((size_t)(N + 1) * 4);
  int*   csr_src  = (int*)alloc((size_t)E * 4);
  unsigned* ebuf  = (unsigned*)alloc((size_t)E * 4);
  int*   bcnt     = (int*)alloc((size_t)NBUK_MAX * 4);
  int*   bof      = (int*)alloc((size_t)(NBUK_MAX + 1) * 4);
  int*   bcur     = (int*)alloc((size_t)NBUK_MAX * 4);
  int*   goff     = (int*)alloc((size_t)(G + 1) * 4);
  float* stats    = (float*)alloc((size_t)nstats * 4);   // 3 x 64 replicas x 256
  (void)ws_size; (void)n_in;

  auto cdiv = [](int a_, int b_) { return (a_ + b_ - 1) / b_; };

  // ---- cooperative graph-structure build (one kernel, 5 phases) ----
  {
    const int* a_src = esrc; const int* a_dst = edst; const int* a_batch = batch;
    int* a_bcnt = bcnt; int* a_bof = bof; int* a_bcur = bcur;
    unsigned* a_ebuf = ebuf; int* a_eoff = eoff; float* a_dis = dis;
    int* a_csr = csr_src; float* a_stats = stats; int* a_goff = goff;
    int a_N = N, a_E = E, a_G = G, a_nbuk = nbuk, a_nstats = nstats;
    void* kargs[] = {
      (void*)&a_src, (void*)&a_dst, (void*)&a_batch, (void*)&a_bcnt,
      (void*)&a_bof, (void*)&a_bcur, (void*)&a_ebuf, (void*)&a_eoff,
      (void*)&a_dis, (void*)&a_csr, (void*)&a_stats, (void*)&a_goff,
      (void*)&a_N, (void*)&a_E, (void*)&a_G, (void*)&a_nbuk, (void*)&a_nstats
    };
    hipLaunchCooperativeKernel((void*)k_graph, dim3(CSR_GRID), dim3(256),
                               kargs, 0, stream);
  }

  // ---- 3 GCN layers (GEMM folds BN from previous layer's replicas) ----
  for (int i = 0; i < 3; ++i) {
    float* statsPrev = stats + (size_t)(i - 1) * LAYER_STATS;  // valid for i>0
    float* statsCur  = stats + (size_t)i * LAYER_STATS;
    if (i == 0)
      k_gemm_mfma<true, true><<<cdiv(N, 128), 512, 0, stream>>>(
          x, W, gamma, beta, stats, dis, hWb, N, invn);
    else
      k_gemm_mfma<false, false><<<cdiv(N, 128), 512, 0, stream>>>(
          h2b, W + (size_t)i * F * F, gamma + (size_t)(i - 1) * F,
          beta + (size_t)(i - 1) * F, statsPrev, dis, hWb, N, invn);
    k_aggregate<<<cdiv(N * 64, 256), 256, 0, stream>>>(hWb, eoff, csr_src, dis,
                                                       b + (size_t)i * F, h2b, N);
    k_stats_b<<<cdiv(N, 256), 256, 0, stream>>>(h2b, statsCur, N);
  }

  // ---- fused pooling + MLP (inline final affine from layer-2 replicas) ----
  k_pool_mlp<<<cdiv(G * 64, 256), 256, 0, stream>>>(h2b, goff,
                                                    gamma + 2 * (size_t)F, beta + 2 * (size_t)F,
                                                    stats + 2 * (size_t)LAYER_STATS,
                                                    hw1, hb1, hw2, hb2, out, G, invn);
}

// Round 17
// 371.650 us; speedup vs baseline: 1.9535x; 1.9535x over previous
//
#include <hip/hip_runtime.h>

// ---------------------------------------------------------------------------
// ReactionGCN: 3-layer GCN (GCNConv + BN + ReLU) -> global_mean_pool -> MLP
// bf16 activations end-to-end (fp32 accumulation):
//   - GEMM = MFMA 16x16x32 bf16, A direct from global, 256 rows/block
//     (2 A-fragments per wave share each B fragment); BN affine computed
//     in-kernel from 64-replica stats and folded into the LDS B-tile
//   - aggregation: one wave per node, 16 gathers in flight (bit-stable floor)
//   - BN stats: separate kernel writing replica (blockIdx&63)
//   - CSR build: 5 separate kernels (r16: cooperative grid.sync fusion was
//     7x SLOWER - cross-XCD sync ~100us each; boundaries are cheaper)
//   - pool+MLP fused, final affine from replicas inline
// ---------------------------------------------------------------------------

typedef __attribute__((ext_vector_type(8))) short short8;
typedef __attribute__((ext_vector_type(4))) float f32x4;

__device__ inline unsigned f32_to_bf16_rne(float f) {
  unsigned u = __float_as_uint(f);
  unsigned r = 0x7fffu + ((u >> 16) & 1u);
  return (u + r) >> 16;
}
__device__ inline unsigned pack2_bf16(float lo, float hi) {
  return f32_to_bf16_rne(lo) | (f32_to_bf16_rne(hi) << 16);
}
__device__ inline float bf16_lo(unsigned u) { return __uint_as_float(u << 16); }
__device__ inline float bf16_hi(unsigned u) { return __uint_as_float(u & 0xffff0000u); }

#define PCH 4096
#define NBUK_MAX 1024
#define NREP 64          // stats replicas per layer
#define REPSZ 256        // floats per replica: [0:128]=ssum, [128:256]=ssq
#define LAYER_STATS (NREP * REPSZ)

// -------------------- init: zero bcnt+stats, compute goff -------------------
__global__ __launch_bounds__(256) void k_init(int* __restrict__ bcnt, int nbuk,
                                              float* __restrict__ stats, int nstats,
                                              const int* __restrict__ batch,
                                              int* __restrict__ goff, int N, int G) {
  int i = blockIdx.x * 256 + threadIdx.x;
  if (i < nbuk) bcnt[i] = 0;
  if (i < nstats) stats[i] = 0.f;
  if (i <= G) {
    int lo = 0, hi = N;
    while (lo < hi) { int mid = (lo + hi) >> 1; if (batch[mid] < i) lo = mid + 1; else hi = mid; }
    goff[i] = lo;
  }
}

// -------------------- bucket counts via LDS histogram -----------------------
__global__ __launch_bounds__(256) void k_bucket_cnt(const int* __restrict__ dst,
                                                    int* __restrict__ bcnt, int E, int nbuk) {
  __shared__ int hist[NBUK_MAX];
  int t = threadIdx.x;
  for (int i = t; i < nbuk; i += 256) hist[i] = 0;
  __syncthreads();
  for (int e = blockIdx.x * 256 + t; e < E; e += gridDim.x * 256)
    atomicAdd(&hist[((unsigned)dst[e]) >> 7], 1);
  __syncthreads();
  for (int i = t; i < nbuk; i += 256) {
    int h = hist[i];
    if (h) atomicAdd(&bcnt[i], h);
  }
}

// -------------------- single-block scan: bcnt -> bof, bcur ------------------
__global__ __launch_bounds__(256) void k_bof_scan(const int* __restrict__ bcnt,
                                                  int* __restrict__ bof,
                                                  int* __restrict__ bcur, int nbuk, int E) {
  int t = threadIdx.x;
  int base = t * 4;
  int v[4]; int s = 0;
#pragma unroll
  for (int k = 0; k < 4; ++k) { v[k] = (base + k < nbuk) ? bcnt[base + k] : 0; s += v[k]; }
  int lane = t & 63, wv = t >> 6;
  int x = s;
#pragma unroll
  for (int d = 1; d < 64; d <<= 1) { int y = __shfl_up(x, d); if (lane >= d) x += y; }
  __shared__ int wsum[4];
  if (lane == 63) wsum[wv] = x;
  __syncthreads();
  int woff = 0;
  for (int w = 0; w < wv; ++w) woff += wsum[w];
  int run = woff + x - s;
#pragma unroll
  for (int k = 0; k < 4; ++k) {
    if (base + k < nbuk) { bof[base + k] = run; bcur[base + k] = run; }
    run += v[k];
  }
  if (t == 0) bof[nbuk] = E;
}

// -------------------- pass C: partition edges into bucket regions -----------
// record = (src<<7) | (dst&127); bucket = dst>>7.
__global__ __launch_bounds__(256) void k_partition(const int* __restrict__ src,
                                                   const int* __restrict__ dst,
                                                   int* __restrict__ bcur,
                                                   unsigned* __restrict__ ebuf,
                                                   int E, int nbuk) {
  __shared__ int hist[NBUK_MAX];
  __shared__ int lofs[NBUK_MAX];
  __shared__ int gbase[NBUK_MAX];
  __shared__ uint2 stage[PCH];
  int t = threadIdx.x;
  int e0 = blockIdx.x * PCH;
  int cnt = E - e0; if (cnt > PCH) cnt = PCH;
  for (int i = t; i < nbuk; i += 256) hist[i] = 0;
  __syncthreads();
  uint2 ev[PCH / 256];
#pragma unroll
  for (int k = 0; k < PCH / 256; ++k) {
    int i = t + k * 256;
    uint2 r = make_uint2(0u, 0u);
    if (i < cnt) {
      r = make_uint2((unsigned)src[e0 + i], (unsigned)dst[e0 + i]);
      atomicAdd(&hist[r.y >> 7], 1);
    }
    ev[k] = r;
  }
  __syncthreads();
  if (t < 64) {
    int run = 0;
    for (int c0 = 0; c0 < nbuk; c0 += 64) {
      int idx = c0 + t;
      int v = (idx < nbuk) ? hist[idx] : 0;
      int x = v;
#pragma unroll
      for (int dlt = 1; dlt < 64; dlt <<= 1) { int y = __shfl_up(x, dlt); if (t >= dlt) x += y; }
      if (idx < nbuk) lofs[idx] = run + x - v;
      run += __shfl(x, 63);
    }
  }
  __syncthreads();
  for (int i = t; i < nbuk; i += 256) {
    int h = hist[i];
    if (h > 0) gbase[i] = atomicAdd(&bcur[i], h);
    hist[i] = 0;
  }
  __syncthreads();
#pragma unroll
  for (int k = 0; k < PCH / 256; ++k) {
    int i = t + k * 256;
    if (i < cnt) {
      uint2 r = ev[k];
      int bk = (int)(r.y >> 7);
      unsigned packed = (r.x << 7) | (r.y & 127u);
      int rank = atomicAdd(&hist[bk], 1);
      stage[lofs[bk] + rank] = make_uint2(packed, (unsigned)bk);
    }
  }
  __syncthreads();
  for (int j = t; j < cnt; j += 256) {
    uint2 s = stage[j];
    int bk = (int)s.y;
    ebuf[(size_t)gbase[bk] + (j - lofs[bk])] = s.x;
  }
}

// -------------------- pass D: fused deg/eoff/dis + CSR placement ------------
__global__ __launch_bounds__(256) void k_bucket_csr2(const unsigned* __restrict__ ebuf,
                                                     const int* __restrict__ bof,
                                                     int* __restrict__ eoff,
                                                     float* __restrict__ dis,
                                                     int* __restrict__ csr_src, int N, int E) {
  __shared__ int lcnt[128];
  __shared__ int loff[128];
  int b = blockIdx.x;
  int n0 = b * 128;
  int t = threadIdx.x;
  int nn = N - n0; if (nn > 128) nn = 128;
  int e0 = bof[b], e1 = bof[b + 1];
  if (t < 128) lcnt[t] = 0;
  __syncthreads();
  for (int j = e0 + t; j < e1; j += 256) atomicAdd(&lcnt[ebuf[j] & 127u], 1);
  __syncthreads();
  if (t < 64) {
    int run = 0;
    for (int c0 = 0; c0 < 128; c0 += 64) {
      int v = lcnt[c0 + t];
      int x = v;
#pragma unroll
      for (int d = 1; d < 64; d <<= 1) { int y = __shfl_up(x, d); if (t >= d) x += y; }
      loff[c0 + t] = run + x - v;
      run += __shfl(x, 63);
    }
  }
  __syncthreads();
  if (t < nn) {
    eoff[n0 + t] = e0 + loff[t];
    dis[n0 + t] = 1.0f / sqrtf((float)lcnt[t] + 1.0f);
  }
  if (b == (int)gridDim.x - 1 && t == nn) eoff[n0 + nn] = E;
  __syncthreads();
  if (t < 128) lcnt[t] = 0;   // reuse as cursor
  __syncthreads();
  for (int j = e0 + t; j < e1; j += 256) {
    unsigned r = ebuf[j];
    int loc = (int)(r & 127u);
    int rank = atomicAdd(&lcnt[loc], 1);
    csr_src[e0 + loff[loc] + rank] = (int)(r >> 7);
  }
}

// -------------------- MFMA GEMM with in-kernel BN fold, 256 rows/block ------
// outb = bf16(dis[r] * (X @ (a.*W) + sum_k c[k]W[k,:]))
// 512 thr = 8 waves; each wave computes rows [w*32, w*32+32): two A-fragments
// (base and +16) share each B fragment. A direct from global (two 8B halves
// per 32-k chunk); folded B built in LDS from raw W + replica stats.
template <bool AFP32, bool IDENT>
__global__ __launch_bounds__(512) void k_gemm_mfma(const void* __restrict__ Xv,
                                                   const float* __restrict__ Wn,
                                                   const float* __restrict__ gamma,
                                                   const float* __restrict__ beta,
                                                   const float* __restrict__ statsL,
                                                   const float* __restrict__ dis,
                                                   unsigned* __restrict__ outb,
                                                   int nrows, float invn) {
  __shared__ uint4 Bsm[2048];          // 32KB folded W, fragment-packed
  __shared__ float as_[128], cs_[128], b2[128];
  int t = threadIdx.x;
  if (t < 128) {
    float a, c;
    if (IDENT) { a = 1.f; c = 0.f; }
    else {
      float s = 0.f, q = 0.f;
#pragma unroll 8
      for (int r = 0; r < NREP; ++r) {
        s += statsL[r * REPSZ + t];
        q += statsL[r * REPSZ + 128 + t];
      }
      float mu  = s * invn;
      float var = q * invn - mu * mu;
      a = gamma[t] / sqrtf(var + 1e-5f);
      c = beta[t] - mu * a;
    }
    as_[t] = a; cs_[t] = c; b2[t] = 0.f;
  }
  __syncthreads();
  // fold raw W into Bsm (2048 uint4 items over 512 threads) + bias partials
#pragma unroll
  for (int it = 0; it < 4; ++it) {
    int item = it * 512 + t;
    int lane = item & 63, bk = (item >> 6) & 7, kstep = item >> 9;
    int col = bk * 16 + (lane & 15);
    int kb = kstep * 32 + ((lane >> 4) << 2);
    unsigned o[4];
    float bp = 0.f;
#pragma unroll
    for (int hh = 0; hh < 2; ++hh)
#pragma unroll
      for (int pp = 0; pp < 2; ++pp) {
        int k0 = kb + hh * 16 + pp * 2;
        float wA = Wn[(size_t)k0 * 128 + col];
        float wB = Wn[(size_t)(k0 + 1) * 128 + col];
        o[hh * 2 + pp] = pack2_bf16(as_[k0] * wA, as_[k0 + 1] * wB);
        bp = fmaf(cs_[k0], wA, fmaf(cs_[k0 + 1], wB, bp));
      }
    Bsm[item] = make_uint4(o[0], o[1], o[2], o[3]);
    atomicAdd(&b2[col], bp);
  }
  __syncthreads();

  int w = t >> 6, l = t & 63;
  int row0 = blockIdx.x * 256 + w * 32;
  int arowA = row0 + (l & 15);
  int arowB = arowA + 16;
  int kgrp = l >> 4;
  bool avalA = arowA < nrows;
  bool avalB = arowB < nrows;
  f32x4 accA[8], accB[8];
#pragma unroll
  for (int i = 0; i < 8; ++i) { accA[i] = (f32x4){0.f, 0.f, 0.f, 0.f}; accB[i] = accA[i]; }
#pragma unroll
  for (int kk = 0; kk < 4; ++kk) {
    union { uint4 u; short8 s; } afA, afB;
    if (AFP32) {
      const float4* X = (const float4*)Xv;   // 32 float4 per row
      float4 a0 = make_float4(0.f, 0.f, 0.f, 0.f), a1 = a0, b0 = a0, b1 = a0;
      if (avalA) {
        size_t bi = (size_t)arowA * 32 + kk * 8 + kgrp;
        a0 = X[bi]; a1 = X[bi + 4];
      }
      if (avalB) {
        size_t bi = (size_t)arowB * 32 + kk * 8 + kgrp;
        b0 = X[bi]; b1 = X[bi + 4];
      }
      afA.u = make_uint4(pack2_bf16(a0.x, a0.y), pack2_bf16(a0.z, a0.w),
                         pack2_bf16(a1.x, a1.y), pack2_bf16(a1.z, a1.w));
      afB.u = make_uint4(pack2_bf16(b0.x, b0.y), pack2_bf16(b0.z, b0.w),
                         pack2_bf16(b1.x, b1.y), pack2_bf16(b1.z, b1.w));
    } else {
      const uint2* X = (const uint2*)Xv;     // 32 uint2 per row
      uint2 a0 = make_uint2(0, 0), a1 = a0, b0 = a0, b1 = a0;
      if (avalA) {
        size_t bi = (size_t)arowA * 32 + kk * 8 + kgrp;
        a0 = X[bi]; a1 = X[bi + 4];
      }
      if (avalB) {
        size_t bi = (size_t)arowB * 32 + kk * 8 + kgrp;
        b0 = X[bi]; b1 = X[bi + 4];
      }
      afA.u = make_uint4(a0.x, a0.y, a1.x, a1.y);
      afB.u = make_uint4(b0.x, b0.y, b1.x, b1.y);
    }
#pragma unroll
    for (int ct = 0; ct < 8; ++ct) {
      union { uint4 u; short8 s; } bf;
      bf.u = Bsm[(kk * 8 + ct) * 64 + l];
      accA[ct] = __builtin_amdgcn_mfma_f32_16x16x32_bf16(afA.s, bf.s, accA[ct], 0, 0, 0);
      accB[ct] = __builtin_amdgcn_mfma_f32_16x16x32_bf16(afB.s, bf.s, accB[ct], 0, 0, 0);
    }
  }
  // D[row=kgrp*4+r][col=ct*16+(l&15)]
  int dcol = l & 15;
#pragma unroll
  for (int r = 0; r < 4; ++r) {
    int growA = row0 + kgrp * 4 + r;
    if (growA < nrows) {
      float dr = dis[growA];
#pragma unroll
      for (int ct = 0; ct < 8; ++ct) {
        int col = ct * 16 + dcol;
        float v = (accA[ct][r] + b2[col]) * dr;
        ((unsigned short*)outb)[(size_t)growA * 128 + col] = (unsigned short)f32_to_bf16_rne(v);
      }
    }
    int growB = growA + 16;
    if (growB < nrows) {
      float dr = dis[growB];
#pragma unroll
      for (int ct = 0; ct < 8; ++ct) {
        int col = ct * 16 + dcol;
        float v = (accB[ct][r] + b2[col]) * dr;
        ((unsigned short*)outb)[(size_t)growB * 128 + col] = (unsigned short)f32_to_bf16_rne(v);
      }
    }
  }
}

// -------------------- aggregation (one wave per node, 16 gathers in flight) -
__global__ __launch_bounds__(256) void k_aggregate(const unsigned* __restrict__ hWb,
                                                   const int* __restrict__ eoff,
                                                   const int* __restrict__ csr_src,
                                                   const float* __restrict__ dis,
                                                   const float* __restrict__ bias,
                                                   unsigned* __restrict__ h2b, int N) {
  int node = __builtin_amdgcn_readfirstlane((int)((blockIdx.x * 256 + threadIdx.x) >> 6));
  int lane = threadIdx.x & 63;
  if (node >= N) return;
  unsigned su = hWb[(size_t)node * 64 + lane];
  float a0 = bf16_lo(su), a1 = bf16_hi(su);
  int p  = eoff[node];
  int e1 = eoff[node + 1];
  int rem = e1 - p;
  while (rem >= 16) {
    int sx[16];
#pragma unroll
    for (int k = 0; k < 16; ++k) sx[k] = csr_src[p + k];
    p += 16; rem -= 16;
    unsigned ux[16];
#pragma unroll
    for (int k = 0; k < 16; ++k) ux[k] = hWb[(size_t)sx[k] * 64 + lane];
#pragma unroll
    for (int k = 0; k < 16; ++k) { a0 += bf16_lo(ux[k]); a1 += bf16_hi(ux[k]); }
  }
  while (rem >= 4) {
    int s0 = csr_src[p], s1 = csr_src[p + 1], s2 = csr_src[p + 2], s3 = csr_src[p + 3];
    p += 4; rem -= 4;
    unsigned u0 = hWb[(size_t)s0 * 64 + lane], u1 = hWb[(size_t)s1 * 64 + lane];
    unsigned u2 = hWb[(size_t)s2 * 64 + lane], u3 = hWb[(size_t)s3 * 64 + lane];
    a0 += bf16_lo(u0); a1 += bf16_hi(u0);
    a0 += bf16_lo(u1); a1 += bf16_hi(u1);
    a0 += bf16_lo(u2); a1 += bf16_hi(u2);
    a0 += bf16_lo(u3); a1 += bf16_hi(u3);
  }
  while (rem) {
    unsigned u0 = hWb[(size_t)csr_src[p] * 64 + lane];
    ++p; --rem;
    a0 += bf16_lo(u0); a1 += bf16_hi(u0);
  }
  float dd = dis[node];
  float2 bb = ((const float2*)bias)[lane];
  float v0 = fmaf(dd, a0, bb.x);
  float v1 = fmaf(dd, a1, bb.y);
  h2b[(size_t)node * 64 + lane] = pack2_bf16(fmaxf(v0, 0.f), fmaxf(v1, 0.f));
}

// -------------------- BN stats on bf16 h2 -> replica (blockIdx&63) ----------
__global__ __launch_bounds__(256) void k_stats_b(const unsigned* __restrict__ h2b,
                                                 float* __restrict__ statsL, int N) {
  int c = threadIdx.x & 63;
  int q = threadIdx.x >> 6;
  int r0 = blockIdx.x * 256;
  int r1 = r0 + 256; if (r1 > N) r1 = N;
  float s0 = 0.f, q0 = 0.f, s1 = 0.f, q1 = 0.f;
  for (int r = r0 + q; r < r1; r += 4) {
    unsigned u = h2b[(size_t)r * 64 + c];
    float h0 = bf16_lo(u), h1 = bf16_hi(u);
    s0 += h0; q0 = fmaf(h0, h0, q0);
    s1 += h1; q1 = fmaf(h1, h1, q1);
  }
  __shared__ float red[4][256];
  int t = threadIdx.x;
  red[0][t] = s0; red[1][t] = q0; red[2][t] = s1; red[3][t] = q1;
  __syncthreads();
  if (t < 64) {
    float S0 = red[0][t] + red[0][t + 64] + red[0][t + 128] + red[0][t + 192];
    float Q0 = red[1][t] + red[1][t + 64] + red[1][t + 128] + red[1][t + 192];
    float S1 = red[2][t] + red[2][t + 64] + red[2][t + 128] + red[2][t + 192];
    float Q1 = red[3][t] + red[3][t + 64] + red[3][t + 128] + red[3][t + 192];
    float* srep = statsL + (size_t)(blockIdx.x & (NREP - 1)) * REPSZ;
    atomicAdd(&srep[2 * t], S0);        atomicAdd(&srep[2 * t + 1], S1);
    atomicAdd(&srep[128 + 2 * t], Q0);  atomicAdd(&srep[128 + 2 * t + 1], Q1);
  }
}

// -------------------- fused pooling + MLP (replica affine inline) -----------
__global__ __launch_bounds__(256) void k_pool_mlp(const unsigned* __restrict__ h2b,
                                                  const int* __restrict__ goff,
                                                  const float* __restrict__ gamma2,
                                                  const float* __restrict__ beta2,
                                                  const float* __restrict__ statsL,
                                                  const float* __restrict__ hw1,
                                                  const float* __restrict__ hb1,
                                                  const float* __restrict__ hw2,
                                                  const float* __restrict__ hb2,
                                                  float* __restrict__ out, int G, float invn) {
  __shared__ float av_[128], cv_[128];
  __shared__ float pl[4][128];
  int t = threadIdx.x;
  if (t < 128) {
    float s = 0.f, q = 0.f;
#pragma unroll 8
    for (int r = 0; r < NREP; ++r) {
      s += statsL[r * REPSZ + t];
      q += statsL[r * REPSZ + 128 + t];
    }
    float mu  = s * invn;
    float var = q * invn - mu * mu;
    float a = gamma2[t] / sqrtf(var + 1e-5f);
    av_[t] = a;
    cv_[t] = beta2[t] - mu * a;
  }
  __syncthreads();
  int g = __builtin_amdgcn_readfirstlane((int)((blockIdx.x * 256 + t) >> 6));
  int lane = t & 63;
  int w = t >> 6;
  if (g >= G) return;
  int r0 = goff[g], r1 = goff[g + 1];
  float s0 = 0.f, s1 = 0.f;
  int r = r0;
  while (r + 4 <= r1) {
    unsigned u0 = h2b[(size_t)(r + 0) * 64 + lane];
    unsigned u1 = h2b[(size_t)(r + 1) * 64 + lane];
    unsigned u2 = h2b[(size_t)(r + 2) * 64 + lane];
    unsigned u3 = h2b[(size_t)(r + 3) * 64 + lane];
    r += 4;
    s0 += bf16_lo(u0); s1 += bf16_hi(u0);
    s0 += bf16_lo(u1); s1 += bf16_hi(u1);
    s0 += bf16_lo(u2); s1 += bf16_hi(u2);
    s0 += bf16_lo(u3); s1 += bf16_hi(u3);
  }
  while (r < r1) {
    unsigned u = h2b[(size_t)r * 64 + lane];
    ++r;
    s0 += bf16_lo(u); s1 += bf16_hi(u);
  }
  float p0 = 0.f, p1 = 0.f;
  if (r1 > r0) {
    float inv = 1.0f / (float)(r1 - r0);
    float2 av = *(const float2*)&av_[2 * lane];
    float2 cv = *(const float2*)&cv_[2 * lane];
    p0 = fmaf(av.x, s0 * inv, cv.x);
    p1 = fmaf(av.y, s1 * inv, cv.y);
  }
  pl[w][2 * lane]     = p0;
  pl[w][2 * lane + 1] = p1;
  // same-wave LDS write->read: single instruction stream, no barrier needed
  float acc = hb1[lane];
  for (int f = 0; f < 128; ++f) acc = fmaf(pl[w][f], hw1[f * 64 + lane], acc);
  acc = fmaxf(acc, 0.f) * hw2[lane];
  for (int d = 32; d; d >>= 1) acc += __shfl_down(acc, d);
  if (lane == 0) out[g] = acc + hb2[0];
}

// ---------------------------------------------------------------------------
extern "C" void kernel_launch(void* const* d_in, const int* in_sizes, int n_in,
                              void* d_out, int out_size, void* d_ws, size_t ws_size,
                              hipStream_t stream) {
  const float* x     = (const float*)d_in[0];
  const int*   ei    = (const int*)d_in[1];
  const int*   batch = (const int*)d_in[2];
  const float* W     = (const float*)d_in[3];
  const float* b     = (const float*)d_in[4];
  const float* gamma = (const float*)d_in[5];
  const float* beta  = (const float*)d_in[6];
  const float* hw1   = (const float*)d_in[7];
  const float* hb1   = (const float*)d_in[8];
  const float* hw2   = (const float*)d_in[9];
  const float* hb2   = (const float*)d_in[10];
  float* out = (float*)d_out;

  const int F = 128;
  const int N = in_sizes[0] / F;
  const int E = in_sizes[1] / 2;
  const int G = out_size;
  const int nbuk = (N + 127) / 128;
  const int nstats = 3 * LAYER_STATS;   // 49152 floats
  const float invn = 1.0f / (float)N;

  const int* esrc = ei;
  const int* edst = ei + E;

  // ---- workspace carve ----
  char* wp = (char*)d_ws;
  auto alloc = [&](size_t bytes) -> void* {
    void* r = (void*)wp;
    wp += (bytes + 255) & ~(size_t)255;
    return r;
  };
  unsigned* hWb   = (unsigned*)alloc((size_t)N * 64 * 4);
  unsigned* h2b   = (unsigned*)alloc((size_t)N * 64 * 4);
  float* dis      = (float*)alloc((size_t)N * 4);
  int*   eoff     = (int*)alloc((size_t)(N + 1) * 4);
  int*   csr_src  = (int*)alloc((size_t)E * 4);
  unsigned* ebuf  = (unsigned*)alloc((size_t)E * 4);
  int*   bcnt     = (int*)alloc((size_t)NBUK_MAX * 4);
  int*   bof      = (int*)alloc((size_t)(NBUK_MAX + 1) * 4);
  int*   bcur     = (int*)alloc((size_t)NBUK_MAX * 4);
  int*   goff     = (int*)alloc((size_t)(G + 1) * 4);
  float* stats    = (float*)alloc((size_t)nstats * 4);   // 3 x 64 replicas x 256
  (void)ws_size; (void)n_in;

  auto cdiv = [](int a_, int b_) { return (a_ + b_ - 1) / b_; };

  // ---- graph structure (once) ----
  int initn = nstats;
  if (initn < G + 1) initn = G + 1;
  if (initn < nbuk) initn = nbuk;
  k_init<<<cdiv(initn, 256), 256, 0, stream>>>(bcnt, nbuk, stats, nstats, batch, goff, N, G);
  k_bucket_cnt<<<256, 256, 0, stream>>>(edst, bcnt, E, nbuk);
  k_bof_scan<<<1, 256, 0, stream>>>(bcnt, bof, bcur, nbuk, E);
  k_partition<<<cdiv(E, PCH), 256, 0, stream>>>(esrc, edst, bcur, ebuf, E, nbuk);
  k_bucket_csr2<<<nbuk, 256, 0, stream>>>(ebuf, bof, eoff, dis, csr_src, N, E);

  // ---- 3 GCN layers (GEMM folds BN from previous layer's replicas) ----
  for (int i = 0; i < 3; ++i) {
    float* statsPrev = stats + (size_t)(i - 1) * LAYER_STATS;  // valid for i>0
    float* statsCur  = stats + (size_t)i * LAYER_STATS;
    if (i == 0)
      k_gemm_mfma<true, true><<<cdiv(N, 256), 512, 0, stream>>>(
          x, W, gamma, beta, stats, dis, hWb, N, invn);
    else
      k_gemm_mfma<false, false><<<cdiv(N, 256), 512, 0, stream>>>(
          h2b, W + (size_t)i * F * F, gamma + (size_t)(i - 1) * F,
          beta + (size_t)(i - 1) * F, statsPrev, dis, hWb, N, invn);
    k_aggregate<<<cdiv(N * 64, 256), 256, 0, stream>>>(hWb, eoff, csr_src, dis,
                                                       b + (size_t)i * F, h2b, N);
    k_stats_b<<<cdiv(N, 256), 256, 0, stream>>>(h2b, statsCur, N);
  }

  // ---- fused pooling + MLP (inline final affine from layer-2 replicas) ----
  k_pool_mlp<<<cdiv(G * 64, 256), 256, 0, stream>>>(h2b, goff,
                                                    gamma + 2 * (size_t)F, beta + 2 * (size_t)F,
                                                    stats + 2 * (size_t)LAYER_STATS,
                                                    hw1, hb1, hw2, hb2, out, G, invn);
}